// Round 11
// baseline (133.567 us; speedup 1.0000x reference)
//
#include <hip/hip_runtime.h>
#include <hip/hip_bf16.h>
#include <hip/hip_fp16.h>

// Problem constants (match setup_inputs): B=2, Y=X=200, N=40000, C=128, H=4, P=8, D=32
#define BQ 2
#define YY 200
#define XX 200
#define NQ 40000
#define CC 128
#define MTOT 80000   // BQ*NQ
#define NCOL 224     // 128 (value) + 64 (off) + 32 (attn logits)
#define NTILES 5000  // MTOT/16

typedef __attribute__((ext_vector_type(8))) short short8;
typedef __attribute__((ext_vector_type(4))) short short4v;
typedef __attribute__((ext_vector_type(4))) float f32x4;

static __device__ __forceinline__ unsigned short f2bf(float f) {
    union { float f; unsigned int u; } v; v.f = f;
    unsigned int r = v.u + 0x7FFF + ((v.u >> 16) & 1);  // round-to-nearest-even
    return (unsigned short)(r >> 16);
}
static __device__ __forceinline__ unsigned short f2bf_hw(float f) {
    __hip_bfloat16 h = __float2bfloat16(f);
    unsigned short s;
    __builtin_memcpy(&s, &h, 2);
    return s;
}
static __device__ __forceinline__ __half2 u2h2(unsigned int u) {
    __half2 h; __builtin_memcpy(&h, &u, 4); return h;
}
static __device__ __forceinline__ unsigned int h22u(__half2 h) {
    unsigned int u; __builtin_memcpy(&u, &h, 4); return u;
}
static __device__ __forceinline__ short h2s(__half h) {
    short s; __builtin_memcpy(&s, &h, 2); return s;
}
static __device__ __forceinline__ unsigned int packh2(float a, float b) {
    return h22u(__floats2half2_rn(a, b));   // low = a, high = b
}

// ---- prep: WcatT[224][128] bf16 = [Wv | Woff | Wattn] transposed ----
__global__ void prep_wcat(const float* __restrict__ Wv, const float* __restrict__ Woff,
                          const float* __restrict__ Wattn, unsigned short* __restrict__ WcatT) {
    int idx = blockIdx.x * 256 + threadIdx.x;       // 224*128 = 28672 = 112 blocks
    if (idx >= NCOL * CC) return;
    int c = idx >> 7, k = idx & 127;
    float w = (c < 128) ? Wv[k * 128 + c]
            : (c < 192) ? Woff[k * 64 + (c - 128)]
                        : Wattn[k * 32 + (c - 192)];
    WcatT[c * 128 + k] = f2bf(w);
}

// ---- prep: W12T[128][128] bf16 = (Wout1@Wout2)^T ; b12 = bout1@Wout2 + bout2 ----
__global__ void prep_w12(const float* __restrict__ Wout1, const float* __restrict__ Wout2,
                         const float* __restrict__ bout1, const float* __restrict__ bout2,
                         unsigned short* __restrict__ W12T, float* __restrict__ b12) {
    int idx = blockIdx.x * 256 + threadIdx.x;       // 16384 = 64 blocks
    int c = idx >> 7, k = idx & 127;
    float s = 0.f;
    for (int j = 0; j < 128; ++j) s += Wout1[k * 128 + j] * Wout2[j * 128 + c];
    W12T[c * 128 + k] = f2bf(s);
    if (k == 0) {
        float t = bout2[c];
        for (int j = 0; j < 128; ++j) t += bout1[j] * Wout2[j * 128 + c];
        b12[c] = t;
    }
}

// ---- G1 (fused qsum): A = bf16(query + qpos) computed in-register per kstep.
// B fully in registers; 4 groups by blockIdx>>8 (siblings same XCD -> L3/L2-shared
// A reads). Swapped-operand MFMA -> 4 consecutive output cols per lane.
// Outputs: value fp16, off fp16, logits fp16.
__global__ __launch_bounds__(256, 2) void g1_kernel(
    const float* __restrict__ query, const float* __restrict__ qpos,
    const unsigned short* __restrict__ WcatT,
    const float* __restrict__ bv, const float* __restrict__ boff, const float* __restrict__ battn,
    unsigned short* __restrict__ value_h, unsigned short* __restrict__ off_h,
    unsigned short* __restrict__ logits_h)
{
    const int tid = threadIdx.x;
    const int group = blockIdx.x >> 8;         // 0..3, siblings same XCD
    const int gblk = blockIdx.x & 255;
    const int lane = tid & 63;
    const int arow = lane & 15, kq = lane >> 4;
    const int wid = gblk * 4 + (tid >> 6);     // 0..1023 within group
    const int tg0 = group * 4;
    const int NT = (group == 3) ? 2 : 4;

    short8 bf[4][4];
#pragma unroll
    for (int t = 0; t < 4; ++t) {
        if (t < NT) {
#pragma unroll
            for (int ks = 0; ks < 4; ++ks)
                bf[t][ks] = *(const short8*)(WcatT + (size_t)((tg0 + t) * 16 + arow) * 128 + ks * 32 + kq * 8);
        }
    }

    f32x4 biasv[4];
#pragma unroll
    for (int t = 0; t < 4; ++t) {
        if (t < NT) {
            const float* bp = (group < 2) ? (bv + (tg0 + t) * 16 + kq * 4)
                            : (group == 2) ? (boff + (tg0 + t - 8) * 16 + kq * 4)
                                           : (battn + (tg0 + t - 12) * 16 + kq * 4);
            float4 b4 = *(const float4*)bp;
            biasv[t] = (f32x4){b4.x, b4.y, b4.z, b4.w};
        }
    }

    for (int tile = wid; tile < NTILES; tile += 1024) {
        const float4* pq = (const float4*)(query + (size_t)(tile * 16 + arow) * 128 + kq * 8);
        const float4* pp = (const float4*)(qpos  + (size_t)(tile * 16 + arow) * 128 + kq * 8);

        f32x4 acc[4];
#pragma unroll
        for (int t = 0; t < 4; ++t) acc[t] = biasv[t];

#pragma unroll
        for (int ks = 0; ks < 4; ++ks) {
            float4 a0 = pq[8 * ks], a1 = pq[8 * ks + 1];
            float4 b0 = pp[8 * ks], b1 = pp[8 * ks + 1];
            short8 af;
            af[0] = (short)f2bf_hw(a0.x + b0.x); af[1] = (short)f2bf_hw(a0.y + b0.y);
            af[2] = (short)f2bf_hw(a0.z + b0.z); af[3] = (short)f2bf_hw(a0.w + b0.w);
            af[4] = (short)f2bf_hw(a1.x + b1.x); af[5] = (short)f2bf_hw(a1.y + b1.y);
            af[6] = (short)f2bf_hw(a1.z + b1.z); af[7] = (short)f2bf_hw(a1.w + b1.w);
#pragma unroll
            for (int t = 0; t < 4; ++t) {
                if (t < NT)   // swapped operands -> transposed fragment
                    acc[t] = __builtin_amdgcn_mfma_f32_16x16x32_bf16(bf[t][ks], af, acc[t], 0, 0, 0);
            }
        }

        const int row = tile * 16 + arow;
        if (group < 2) {
#pragma unroll
            for (int t = 0; t < 4; ++t) {
                short4v pv;
                pv[0] = h2s(__float2half(acc[t][0])); pv[1] = h2s(__float2half(acc[t][1]));
                pv[2] = h2s(__float2half(acc[t][2])); pv[3] = h2s(__float2half(acc[t][3]));
                *(short4v*)(value_h + (size_t)row * 128 + (tg0 + t) * 16 + kq * 4) = pv;
            }
        } else if (group == 2) {
#pragma unroll
            for (int t = 0; t < 4; ++t) {
                uint2 pk;
                pk.x = packh2(acc[t][0], acc[t][1]);
                pk.y = packh2(acc[t][2], acc[t][3]);
                *(uint2*)(off_h + (size_t)row * 64 + (tg0 + t - 8) * 16 + kq * 4) = pk;
            }
        } else {
#pragma unroll
            for (int t = 0; t < 2; ++t) {
                uint2 pk;
                pk.x = packh2(acc[t][0], acc[t][1]);
                pk.y = packh2(acc[t][2], acc[t][3]);
                *(uint2*)(logits_h + (size_t)row * 32 + (tg0 + t - 12) * 16 + kq * 4) = pk;
            }
        }
    }
}

// ---- sampling: batched-MLP gather (unchanged structure), fp16 off/logits inputs.
__global__ __launch_bounds__(256) void sample_kernel(
    const unsigned short* __restrict__ value_h, const unsigned short* __restrict__ off_h,
    const unsigned short* __restrict__ logits_h, unsigned short* __restrict__ sampled)
{
    __shared__ int4 SA[8][36];   // (a00,a01,a10,a11) corner byte-addresses
    __shared__ int4 SW[8][36];   // (w00,w01,w10,w11) dup'd half2 corner weights

    const int tid = threadIdx.x;
    const int qi = tid >> 5;
    const int lane = tid & 31;
    const int r = blockIdx.x * 8 + qi;          // query row, 0..79999
    const int b = (r >= NQ) ? 1 : 0;
    const int n = r - b * NQ;
    const int yq = n / XX, xq = n - yq * XX;

    // ---- phase 1: per-sample setup (lane = h*8+p) ----
    {
        float lg = __half2float(*(const __half*)(logits_h + (size_t)r * 32 + lane));
        float m = lg;
        m = fmaxf(m, __shfl_xor(m, 1));
        m = fmaxf(m, __shfl_xor(m, 2));
        m = fmaxf(m, __shfl_xor(m, 4));
        float e = __expf(lg - m);
        float s = e;
        s += __shfl_xor(s, 1);
        s += __shfl_xor(s, 2);
        s += __shfl_xor(s, 4);
        float aw = e / s;

        // faithful reference quirk: x-coord = yq + off0, y-coord = xq + off1
        __half2 oh = u2h2(*(const unsigned int*)(off_h + (size_t)r * 64 + lane * 2));
        float gx = (float)yq + __low2float(oh);
        float gy = (float)xq + __high2float(oh);
        float fx = floorf(gx), fy = floorf(gy);
        int x0 = (int)fx, y0 = (int)fy;
        float wx1 = gx - fx, wy1 = gy - fy;
        float vx0 = ((unsigned)x0 < XX) ? 1.f : 0.f;
        float vx1 = ((unsigned)(x0 + 1) < XX) ? 1.f : 0.f;
        float vy0 = ((unsigned)y0 < YY) ? 1.f : 0.f;
        float vy1 = ((unsigned)(y0 + 1) < YY) ? 1.f : 0.f;
        int x0c = min(max(x0, 0), XX - 1);
        int x1c = min(max(x0 + 1, 0), XX - 1);
        int y0c = min(max(y0, 0), YY - 1);
        int y1c = min(max(y0 + 1, 0), YY - 1);
        int hb = (lane >> 3) * 64;                 // head byte offset within 256B row
        int rowA = y0c * XX, rowB = y1c * XX;
        int4 addrs;
        addrs.x = (rowA + x0c) * 256 + hb;
        addrs.y = (rowA + x1c) * 256 + hb;
        addrs.z = (rowB + x0c) * 256 + hb;
        addrs.w = (rowB + x1c) * 256 + hb;

        float wxa = (1.f - wx1) * vx0;
        float wxb = wx1 * vx1;
        float wya = aw * (1.f - wy1) * vy0;
        float wyb = aw * wy1 * vy1;
        int4 wts;
        wts.x = (int)h22u(__float2half2_rn(wxa * wya));   // w00
        wts.y = (int)h22u(__float2half2_rn(wxb * wya));   // w01
        wts.z = (int)h22u(__float2half2_rn(wxa * wyb));   // w10
        wts.w = (int)h22u(__float2half2_rn(wxb * wyb));   // w11

        const int slot = (lane & 7) * 4 + (lane >> 3);    // 4p + h
        SA[qi][slot] = addrs;
        SW[qi][slot] = wts;
    }
    __syncthreads();

    // ---- phase 2: lane = h*8 + yc*4 + quad ----
    const char* vb = (const char*)(value_h + (size_t)b * NQ * 128);
    const int h = lane >> 3, yc = (lane >> 2) & 1, quad = lane & 3;
    const int cb = quad * 16;                   // 16B (8 fp16 channels) within head row

    // batch-read this lane's 8 (x0,x1) address pairs for its y-row
    int2 a[8];
#pragma unroll
    for (int p = 0; p < 8; ++p)
        a[p] = *(const int2*)((const char*)&SA[qi][p * 4 + h] + yc * 8);

    // issue ALL 16 gathers before any use
    uint4 d0[8], d1[8];
#pragma unroll
    for (int p = 0; p < 8; ++p) {
        d0[p] = *(const uint4*)(vb + a[p].x + cb);
        d1[p] = *(const uint4*)(vb + a[p].y + cb);
    }

    // weights (LDS latency hides under the VMEM queue)
    int2 w[8];
#pragma unroll
    for (int p = 0; p < 8; ++p)
        w[p] = *(const int2*)((const char*)&SW[qi][p * 4 + h] + yc * 8);

    __half2 acc0 = __float2half2_rn(0.f), acc1 = __float2half2_rn(0.f);
    __half2 acc2 = __float2half2_rn(0.f), acc3 = __float2half2_rn(0.f);

#pragma unroll
    for (int p = 0; p < 8; ++p) {
        __half2 wa = u2h2((unsigned int)w[p].x);
        __half2 wb = u2h2((unsigned int)w[p].y);
        acc0 = __hfma2(wa, u2h2(d0[p].x), acc0);
        acc1 = __hfma2(wa, u2h2(d0[p].y), acc1);
        acc2 = __hfma2(wa, u2h2(d0[p].z), acc2);
        acc3 = __hfma2(wa, u2h2(d0[p].w), acc3);
        acc0 = __hfma2(wb, u2h2(d1[p].x), acc0);
        acc1 = __hfma2(wb, u2h2(d1[p].y), acc1);
        acc2 = __hfma2(wb, u2h2(d1[p].z), acc2);
        acc3 = __hfma2(wb, u2h2(d1[p].w), acc3);
    }

    // combine the two y-rows (lanes yc=0/1 differ by bit 2)
    acc0 = __hadd2(acc0, u2h2((unsigned int)__shfl_xor((int)h22u(acc0), 4)));
    acc1 = __hadd2(acc1, u2h2((unsigned int)__shfl_xor((int)h22u(acc1), 4)));
    acc2 = __hadd2(acc2, u2h2((unsigned int)__shfl_xor((int)h22u(acc2), 4)));
    acc3 = __hadd2(acc3, u2h2((unsigned int)__shfl_xor((int)h22u(acc3), 4)));

    // each yc-half stores 8B (4 bf16 channels): yc=0 -> acc0/acc1, yc=1 -> acc2/acc3
    __half2 pa = (yc == 0) ? acc0 : acc2;
    __half2 pb = (yc == 0) ? acc1 : acc3;
    uint2 packed;
    packed.x = ((unsigned int)f2bf(__high2float(pa)) << 16) | (unsigned int)f2bf(__low2float(pa));
    packed.y = ((unsigned int)f2bf(__high2float(pb)) << 16) | (unsigned int)f2bf(__low2float(pb));
    *(uint2*)((char*)(sampled + (size_t)r * 128) + h * 64 + cb + yc * 8) = packed;
}

// ---- G2: out = sampled @ W12 + b12 + query. B in registers, 2 groups of 4 tiles
// (siblings same XCD), swapped MFMA -> float4 stores with fused residual read. ----
__global__ __launch_bounds__(256, 2) void g2_kernel(
    const unsigned short* __restrict__ sampled, const unsigned short* __restrict__ W12T,
    const float* __restrict__ b12, const float* __restrict__ query, float* __restrict__ out)
{
    const int tid = threadIdx.x;
    const int group = blockIdx.x >> 9;         // 0..1, siblings same XCD
    const int gblk = blockIdx.x & 511;
    const int lane = tid & 63;
    const int arow = lane & 15, kq = lane >> 4;
    const int wid = gblk * 4 + (tid >> 6);     // 0..2047 within group
    const int tg0 = group * 4;

    short8 bf[4][4];
#pragma unroll
    for (int t = 0; t < 4; ++t)
#pragma unroll
        for (int ks = 0; ks < 4; ++ks)
            bf[t][ks] = *(const short8*)(W12T + (size_t)((tg0 + t) * 16 + arow) * 128 + ks * 32 + kq * 8);

    f32x4 biasv[4];
#pragma unroll
    for (int t = 0; t < 4; ++t) {
        float4 b4 = *(const float4*)(b12 + (tg0 + t) * 16 + kq * 4);
        biasv[t] = (f32x4){b4.x, b4.y, b4.z, b4.w};
    }

    for (int tile = wid; tile < NTILES; tile += 2048) {
        const char* pa = (const char*)sampled + (size_t)(tile * 16 + arow) * 256 + kq * 16;
        short8 af[4];
#pragma unroll
        for (int ks = 0; ks < 4; ++ks) af[ks] = *(const short8*)(pa + ks * 64);

        f32x4 acc[4];
#pragma unroll
        for (int t = 0; t < 4; ++t) acc[t] = biasv[t];

#pragma unroll
        for (int ks = 0; ks < 4; ++ks)
#pragma unroll
            for (int t = 0; t < 4; ++t)
                acc[t] = __builtin_amdgcn_mfma_f32_16x16x32_bf16(bf[t][ks], af[ks], acc[t], 0, 0, 0);

        const int row = tile * 16 + arow;
#pragma unroll
        for (int t = 0; t < 4; ++t) {
            size_t idx = (size_t)row * 128 + (tg0 + t) * 16 + kq * 4;
            float4 q4 = *(const float4*)(query + idx);
            float4 o = make_float4(acc[t][0] + q4.x, acc[t][1] + q4.y,
                                   acc[t][2] + q4.z, acc[t][3] + q4.w);
            *(float4*)(out + idx) = o;
        }
    }
}

extern "C" void kernel_launch(void* const* d_in, const int* in_sizes, int n_in,
                              void* d_out, int out_size, void* d_ws, size_t ws_size,
                              hipStream_t stream) {
    const float* query = (const float*)d_in[0];
    const float* qpos  = (const float*)d_in[1];
    const float* Wv    = (const float*)d_in[2];
    const float* bv    = (const float*)d_in[3];
    const float* Woff  = (const float*)d_in[4];
    const float* boff  = (const float*)d_in[5];
    const float* Wattn = (const float*)d_in[6];
    const float* battn = (const float*)d_in[7];
    const float* Wout1 = (const float*)d_in[8];
    const float* bout1 = (const float*)d_in[9];
    const float* Wout2 = (const float*)d_in[10];
    const float* bout2 = (const float*)d_in[11];
    float* out = (float*)d_out;

    char* ws = (char*)d_ws;
    unsigned short* value_h  = (unsigned short*)(ws);                 // 80000*128*2 = 20,480,000 (fp16)
    unsigned short* off_h    = (unsigned short*)(ws + 20480000);      // 80000*64*2  = 10,240,000 (fp16)
    unsigned short* logits_h = (unsigned short*)(ws + 40960000);      // 80000*32*2  =  5,120,000 (fp16)
    unsigned short* sampled  = (unsigned short*)(ws + 51200000);      // 80000*128*2 = 20,480,000
    unsigned short* WcatT    = (unsigned short*)(ws + 71680000);      // 224*128*2   = 57,344
    unsigned short* W12T     = (unsigned short*)(ws + 71680000 + 57344);  // 128*128*2 = 32,768
    float*          b12      = (float*)(ws + 71680000 + 57344 + 32768);   // 512

    prep_wcat<<<112, 256, 0, stream>>>(Wv, Woff, Wattn, WcatT);
    prep_w12<<<64, 256, 0, stream>>>(Wout1, Wout2, bout1, bout2, W12T, b12);
    g1_kernel<<<1024, 256, 0, stream>>>(query, qpos, WcatT, bv, boff, battn,
                                        value_h, off_h, logits_h);
    sample_kernel<<<MTOT / 8, 256, 0, stream>>>(value_h, off_h, logits_h, sampled);
    g2_kernel<<<1024, 256, 0, stream>>>(sampled, W12T, b12, query, out);
}

// Round 12
// 109.782 us; speedup vs baseline: 1.2167x; 1.2167x over previous
//
#include <hip/hip_runtime.h>
#include <hip/hip_bf16.h>
#include <hip/hip_fp16.h>

// Problem constants (match setup_inputs): B=2, Y=X=200, N=40000, C=128, H=4, P=8, D=32
#define BQ 2
#define YY 200
#define XX 200
#define NQ 40000
#define CC 128
#define MTOT 80000   // BQ*NQ
#define NCOL 224     // 128 (value) + 64 (off) + 32 (attn logits)
#define NTILES 5000  // MTOT/16

typedef __attribute__((ext_vector_type(8))) short short8;
typedef __attribute__((ext_vector_type(4))) short short4v;
typedef __attribute__((ext_vector_type(4))) float f32x4;

static __device__ __forceinline__ unsigned short f2bf(float f) {
    union { float f; unsigned int u; } v; v.f = f;
    unsigned int r = v.u + 0x7FFF + ((v.u >> 16) & 1);  // round-to-nearest-even
    return (unsigned short)(r >> 16);
}
static __device__ __forceinline__ unsigned short f2bf_hw(float f) {
    __hip_bfloat16 h = __float2bfloat16(f);
    unsigned short s;
    __builtin_memcpy(&s, &h, 2);
    return s;
}
static __device__ __forceinline__ __half2 u2h2(unsigned int u) {
    __half2 h; __builtin_memcpy(&h, &u, 4); return h;
}
static __device__ __forceinline__ unsigned int h22u(__half2 h) {
    unsigned int u; __builtin_memcpy(&u, &h, 4); return u;
}
static __device__ __forceinline__ short h2s(__half h) {
    short s; __builtin_memcpy(&s, &h, 2); return s;
}
static __device__ __forceinline__ unsigned int packh2(float a, float b) {
    return h22u(__floats2half2_rn(a, b));   // low = a, high = b
}

// ---- prep: WcatT[224][128] bf16 = [Wv | Woff | Wattn] transposed ----
__global__ void prep_wcat(const float* __restrict__ Wv, const float* __restrict__ Woff,
                          const float* __restrict__ Wattn, unsigned short* __restrict__ WcatT) {
    int idx = blockIdx.x * 256 + threadIdx.x;       // 224*128 = 28672 = 112 blocks
    if (idx >= NCOL * CC) return;
    int c = idx >> 7, k = idx & 127;
    float w = (c < 128) ? Wv[k * 128 + c]
            : (c < 192) ? Woff[k * 64 + (c - 128)]
                        : Wattn[k * 32 + (c - 192)];
    WcatT[c * 128 + k] = f2bf(w);
}

// ---- prep: W12T[128][128] bf16 = (Wout1@Wout2)^T ; b12 = bout1@Wout2 + bout2 ----
__global__ void prep_w12(const float* __restrict__ Wout1, const float* __restrict__ Wout2,
                         const float* __restrict__ bout1, const float* __restrict__ bout2,
                         unsigned short* __restrict__ W12T, float* __restrict__ b12) {
    int idx = blockIdx.x * 256 + threadIdx.x;       // 16384 = 64 blocks
    int c = idx >> 7, k = idx & 127;
    float s = 0.f;
    for (int j = 0; j < 128; ++j) s += Wout1[k * 128 + j] * Wout2[j * 128 + c];
    W12T[c * 128 + k] = f2bf(s);
    if (k == 0) {
        float t = bout2[c];
        for (int j = 0; j < 128; ++j) t += bout1[j] * Wout2[j * 128 + c];
        b12[c] = t;
    }
}

// ---- qsum: q_bf = bf16(query + qpos), pure streaming ----
__global__ __launch_bounds__(256) void qsum_kernel(const float* __restrict__ query,
                                                   const float* __restrict__ qpos,
                                                   unsigned short* __restrict__ qbf) {
    const size_t total = (size_t)MTOT * CC / 8;   // 1,280,000 chunks of 8 floats
    for (size_t c = (size_t)blockIdx.x * 256 + threadIdx.x; c < total;
         c += (size_t)gridDim.x * 256) {
        const float4* a = (const float4*)(query + c * 8);
        const float4* b = (const float4*)(qpos + c * 8);
        float4 a0 = a[0], a1 = a[1], b0 = b[0], b1 = b[1];
        short8 w;
        w[0] = (short)f2bf_hw(a0.x + b0.x); w[1] = (short)f2bf_hw(a0.y + b0.y);
        w[2] = (short)f2bf_hw(a0.z + b0.z); w[3] = (short)f2bf_hw(a0.w + b0.w);
        w[4] = (short)f2bf_hw(a1.x + b1.x); w[5] = (short)f2bf_hw(a1.y + b1.y);
        w[6] = (short)f2bf_hw(a1.z + b1.z); w[7] = (short)f2bf_hw(a1.w + b1.w);
        *(short8*)(qbf + c * 8) = w;
    }
}

// ---- G1: projection GEMM, B fully in REGISTERS (no LDS, no barrier).
// A = qbf (bf16, 64B/lane). 4 groups by blockIdx>>8 (siblings same XCD).
// Swapped-operand MFMA -> 4 consecutive output cols per lane.
// Outputs: value fp16, off fp16, logits fp16.
__global__ __launch_bounds__(256, 2) void g1_kernel(
    const unsigned short* __restrict__ qbf, const unsigned short* __restrict__ WcatT,
    const float* __restrict__ bv, const float* __restrict__ boff, const float* __restrict__ battn,
    unsigned short* __restrict__ value_h, unsigned short* __restrict__ off_h,
    unsigned short* __restrict__ logits_h)
{
    const int tid = threadIdx.x;
    const int group = blockIdx.x >> 8;         // 0..3, siblings same XCD
    const int gblk = blockIdx.x & 255;
    const int lane = tid & 63;
    const int arow = lane & 15, kq = lane >> 4;
    const int wid = gblk * 4 + (tid >> 6);     // 0..1023 within group
    const int tg0 = group * 4;
    const int NT = (group == 3) ? 2 : 4;

    short8 bf[4][4];
#pragma unroll
    for (int t = 0; t < 4; ++t) {
        if (t < NT) {
#pragma unroll
            for (int ks = 0; ks < 4; ++ks)
                bf[t][ks] = *(const short8*)(WcatT + (size_t)((tg0 + t) * 16 + arow) * 128 + ks * 32 + kq * 8);
        }
    }

    f32x4 biasv[4];
#pragma unroll
    for (int t = 0; t < 4; ++t) {
        if (t < NT) {
            const float* bp = (group < 2) ? (bv + (tg0 + t) * 16 + kq * 4)
                            : (group == 2) ? (boff + (tg0 + t - 8) * 16 + kq * 4)
                                           : (battn + (tg0 + t - 12) * 16 + kq * 4);
            float4 b4 = *(const float4*)bp;
            biasv[t] = (f32x4){b4.x, b4.y, b4.z, b4.w};
        }
    }

    for (int tile = wid; tile < NTILES; tile += 1024) {
        const char* pa = (const char*)qbf + (size_t)(tile * 16 + arow) * 256 + kq * 16;
        short8 af[4];
#pragma unroll
        for (int ks = 0; ks < 4; ++ks) af[ks] = *(const short8*)(pa + ks * 64);

        f32x4 acc[4];
#pragma unroll
        for (int t = 0; t < 4; ++t) acc[t] = biasv[t];

#pragma unroll
        for (int ks = 0; ks < 4; ++ks) {
#pragma unroll
            for (int t = 0; t < 4; ++t) {
                if (t < NT)   // swapped operands -> transposed fragment
                    acc[t] = __builtin_amdgcn_mfma_f32_16x16x32_bf16(bf[t][ks], af[ks], acc[t], 0, 0, 0);
            }
        }

        const int row = tile * 16 + arow;
        if (group < 2) {
#pragma unroll
            for (int t = 0; t < 4; ++t) {
                short4v pv;
                pv[0] = h2s(__float2half(acc[t][0])); pv[1] = h2s(__float2half(acc[t][1]));
                pv[2] = h2s(__float2half(acc[t][2])); pv[3] = h2s(__float2half(acc[t][3]));
                *(short4v*)(value_h + (size_t)row * 128 + (tg0 + t) * 16 + kq * 4) = pv;
            }
        } else if (group == 2) {
#pragma unroll
            for (int t = 0; t < 4; ++t) {
                uint2 pk;
                pk.x = packh2(acc[t][0], acc[t][1]);
                pk.y = packh2(acc[t][2], acc[t][3]);
                *(uint2*)(off_h + (size_t)row * 64 + (tg0 + t - 8) * 16 + kq * 4) = pk;
            }
        } else {
#pragma unroll
            for (int t = 0; t < 2; ++t) {
                uint2 pk;
                pk.x = packh2(acc[t][0], acc[t][1]);
                pk.y = packh2(acc[t][2], acc[t][3]);
                *(uint2*)(logits_h + (size_t)row * 32 + (tg0 + t - 12) * 16 + kq * 4) = pk;
            }
        }
    }
}

// ---- sampling: batched-MLP gather; fp16 off/logits inputs. Phase 1 (lane=h*8+p):
// softmax + folded corner weights -> LDS (row stride 36 int4 = disjoint bank spans).
// Phase 2 (lane=h,yc,quad): ALL 16 uint4 gathers issued before any use.
__global__ __launch_bounds__(256) void sample_kernel(
    const unsigned short* __restrict__ value_h, const unsigned short* __restrict__ off_h,
    const unsigned short* __restrict__ logits_h, unsigned short* __restrict__ sampled)
{
    __shared__ int4 SA[8][36];   // (a00,a01,a10,a11) corner byte-addresses
    __shared__ int4 SW[8][36];   // (w00,w01,w10,w11) dup'd half2 corner weights

    const int tid = threadIdx.x;
    const int qi = tid >> 5;
    const int lane = tid & 31;
    const int r = blockIdx.x * 8 + qi;          // query row, 0..79999
    const int b = (r >= NQ) ? 1 : 0;
    const int n = r - b * NQ;
    const int yq = n / XX, xq = n - yq * XX;

    // ---- phase 1: per-sample setup (lane = h*8+p) ----
    {
        float lg = __half2float(*(const __half*)(logits_h + (size_t)r * 32 + lane));
        float m = lg;
        m = fmaxf(m, __shfl_xor(m, 1));
        m = fmaxf(m, __shfl_xor(m, 2));
        m = fmaxf(m, __shfl_xor(m, 4));
        float e = __expf(lg - m);
        float s = e;
        s += __shfl_xor(s, 1);
        s += __shfl_xor(s, 2);
        s += __shfl_xor(s, 4);
        float aw = e / s;

        // faithful reference quirk: x-coord = yq + off0, y-coord = xq + off1
        __half2 oh = u2h2(*(const unsigned int*)(off_h + (size_t)r * 64 + lane * 2));
        float gx = (float)yq + __low2float(oh);
        float gy = (float)xq + __high2float(oh);
        float fx = floorf(gx), fy = floorf(gy);
        int x0 = (int)fx, y0 = (int)fy;
        float wx1 = gx - fx, wy1 = gy - fy;
        float vx0 = ((unsigned)x0 < XX) ? 1.f : 0.f;
        float vx1 = ((unsigned)(x0 + 1) < XX) ? 1.f : 0.f;
        float vy0 = ((unsigned)y0 < YY) ? 1.f : 0.f;
        float vy1 = ((unsigned)(y0 + 1) < YY) ? 1.f : 0.f;
        int x0c = min(max(x0, 0), XX - 1);
        int x1c = min(max(x0 + 1, 0), XX - 1);
        int y0c = min(max(y0, 0), YY - 1);
        int y1c = min(max(y0 + 1, 0), YY - 1);
        int hb = (lane >> 3) * 64;                 // head byte offset within 256B row
        int rowA = y0c * XX, rowB = y1c * XX;
        int4 addrs;
        addrs.x = (rowA + x0c) * 256 + hb;
        addrs.y = (rowA + x1c) * 256 + hb;
        addrs.z = (rowB + x0c) * 256 + hb;
        addrs.w = (rowB + x1c) * 256 + hb;

        float wxa = (1.f - wx1) * vx0;
        float wxb = wx1 * vx1;
        float wya = aw * (1.f - wy1) * vy0;
        float wyb = aw * wy1 * vy1;
        int4 wts;
        wts.x = (int)h22u(__float2half2_rn(wxa * wya));   // w00
        wts.y = (int)h22u(__float2half2_rn(wxb * wya));   // w01
        wts.z = (int)h22u(__float2half2_rn(wxa * wyb));   // w10
        wts.w = (int)h22u(__float2half2_rn(wxb * wyb));   // w11

        const int slot = (lane & 7) * 4 + (lane >> 3);    // 4p + h
        SA[qi][slot] = addrs;
        SW[qi][slot] = wts;
    }
    __syncthreads();

    // ---- phase 2: lane = h*8 + yc*4 + quad ----
    const char* vb = (const char*)(value_h + (size_t)b * NQ * 128);
    const int h = lane >> 3, yc = (lane >> 2) & 1, quad = lane & 3;
    const int cb = quad * 16;                   // 16B (8 fp16 channels) within head row

    // batch-read this lane's 8 (x0,x1) address pairs for its y-row
    int2 a[8];
#pragma unroll
    for (int p = 0; p < 8; ++p)
        a[p] = *(const int2*)((const char*)&SA[qi][p * 4 + h] + yc * 8);

    // issue ALL 16 gathers before any use
    uint4 d0[8], d1[8];
#pragma unroll
    for (int p = 0; p < 8; ++p) {
        d0[p] = *(const uint4*)(vb + a[p].x + cb);
        d1[p] = *(const uint4*)(vb + a[p].y + cb);
    }

    // weights (LDS latency hides under the VMEM queue)
    int2 w[8];
#pragma unroll
    for (int p = 0; p < 8; ++p)
        w[p] = *(const int2*)((const char*)&SW[qi][p * 4 + h] + yc * 8);

    __half2 acc0 = __float2half2_rn(0.f), acc1 = __float2half2_rn(0.f);
    __half2 acc2 = __float2half2_rn(0.f), acc3 = __float2half2_rn(0.f);

#pragma unroll
    for (int p = 0; p < 8; ++p) {
        __half2 wa = u2h2((unsigned int)w[p].x);
        __half2 wb = u2h2((unsigned int)w[p].y);
        acc0 = __hfma2(wa, u2h2(d0[p].x), acc0);
        acc1 = __hfma2(wa, u2h2(d0[p].y), acc1);
        acc2 = __hfma2(wa, u2h2(d0[p].z), acc2);
        acc3 = __hfma2(wa, u2h2(d0[p].w), acc3);
        acc0 = __hfma2(wb, u2h2(d1[p].x), acc0);
        acc1 = __hfma2(wb, u2h2(d1[p].y), acc1);
        acc2 = __hfma2(wb, u2h2(d1[p].z), acc2);
        acc3 = __hfma2(wb, u2h2(d1[p].w), acc3);
    }

    // combine the two y-rows (lanes yc=0/1 differ by bit 2)
    acc0 = __hadd2(acc0, u2h2((unsigned int)__shfl_xor((int)h22u(acc0), 4)));
    acc1 = __hadd2(acc1, u2h2((unsigned int)__shfl_xor((int)h22u(acc1), 4)));
    acc2 = __hadd2(acc2, u2h2((unsigned int)__shfl_xor((int)h22u(acc2), 4)));
    acc3 = __hadd2(acc3, u2h2((unsigned int)__shfl_xor((int)h22u(acc3), 4)));

    // each yc-half stores 8B (4 bf16 channels): yc=0 -> acc0/acc1, yc=1 -> acc2/acc3
    __half2 pa = (yc == 0) ? acc0 : acc2;
    __half2 pb = (yc == 0) ? acc1 : acc3;
    uint2 packed;
    packed.x = ((unsigned int)f2bf(__high2float(pa)) << 16) | (unsigned int)f2bf(__low2float(pa));
    packed.y = ((unsigned int)f2bf(__high2float(pb)) << 16) | (unsigned int)f2bf(__low2float(pb));
    *(uint2*)((char*)(sampled + (size_t)r * 128) + h * 64 + cb + yc * 8) = packed;
}

// ---- G2: out = sampled @ W12 + b12 + query. B in registers, 2 groups of 4 tiles
// (siblings same XCD), swapped MFMA -> float4 stores with fused residual read. ----
__global__ __launch_bounds__(256, 2) void g2_kernel(
    const unsigned short* __restrict__ sampled, const unsigned short* __restrict__ W12T,
    const float* __restrict__ b12, const float* __restrict__ query, float* __restrict__ out)
{
    const int tid = threadIdx.x;
    const int group = blockIdx.x >> 9;         // 0..1, siblings same XCD
    const int gblk = blockIdx.x & 511;
    const int lane = tid & 63;
    const int arow = lane & 15, kq = lane >> 4;
    const int wid = gblk * 4 + (tid >> 6);     // 0..2047 within group
    const int tg0 = group * 4;

    short8 bf[4][4];
#pragma unroll
    for (int t = 0; t < 4; ++t)
#pragma unroll
        for (int ks = 0; ks < 4; ++ks)
            bf[t][ks] = *(const short8*)(W12T + (size_t)((tg0 + t) * 16 + arow) * 128 + ks * 32 + kq * 8);

    f32x4 biasv[4];
#pragma unroll
    for (int t = 0; t < 4; ++t) {
        float4 b4 = *(const float4*)(b12 + (tg0 + t) * 16 + kq * 4);
        biasv[t] = (f32x4){b4.x, b4.y, b4.z, b4.w};
    }

    for (int tile = wid; tile < NTILES; tile += 2048) {
        const char* pa = (const char*)sampled + (size_t)(tile * 16 + arow) * 256 + kq * 16;
        short8 af[4];
#pragma unroll
        for (int ks = 0; ks < 4; ++ks) af[ks] = *(const short8*)(pa + ks * 64);

        f32x4 acc[4];
#pragma unroll
        for (int t = 0; t < 4; ++t) acc[t] = biasv[t];

#pragma unroll
        for (int ks = 0; ks < 4; ++ks)
#pragma unroll
            for (int t = 0; t < 4; ++t)
                acc[t] = __builtin_amdgcn_mfma_f32_16x16x32_bf16(bf[t][ks], af[ks], acc[t], 0, 0, 0);

        const int row = tile * 16 + arow;
#pragma unroll
        for (int t = 0; t < 4; ++t) {
            size_t idx = (size_t)row * 128 + (tg0 + t) * 16 + kq * 4;
            float4 q4 = *(const float4*)(query + idx);
            float4 o = make_float4(acc[t][0] + q4.x, acc[t][1] + q4.y,
                                   acc[t][2] + q4.z, acc[t][3] + q4.w);
            *(float4*)(out + idx) = o;
        }
    }
}

extern "C" void kernel_launch(void* const* d_in, const int* in_sizes, int n_in,
                              void* d_out, int out_size, void* d_ws, size_t ws_size,
                              hipStream_t stream) {
    const float* query = (const float*)d_in[0];
    const float* qpos  = (const float*)d_in[1];
    const float* Wv    = (const float*)d_in[2];
    const float* bv    = (const float*)d_in[3];
    const float* Woff  = (const float*)d_in[4];
    const float* boff  = (const float*)d_in[5];
    const float* Wattn = (const float*)d_in[6];
    const float* battn = (const float*)d_in[7];
    const float* Wout1 = (const float*)d_in[8];
    const float* bout1 = (const float*)d_in[9];
    const float* Wout2 = (const float*)d_in[10];
    const float* bout2 = (const float*)d_in[11];
    float* out = (float*)d_out;

    char* ws = (char*)d_ws;
    unsigned short* value_h  = (unsigned short*)(ws);                 // 80000*128*2 = 20,480,000 (fp16)
    unsigned short* off_h    = (unsigned short*)(ws + 20480000);      // 80000*64*2  = 10,240,000 (fp16)
    unsigned short* logits_h = (unsigned short*)(ws + 40960000);      // 80000*32*2  =  5,120,000 (fp16)
    unsigned short* sampled  = (unsigned short*)(ws + 51200000);      // 80000*128*2 = 20,480,000
    unsigned short* WcatT    = (unsigned short*)(ws + 71680000);      // 224*128*2   = 57,344
    unsigned short* W12T     = (unsigned short*)(ws + 71680000 + 57344);  // 128*128*2 = 32,768
    float*          b12      = (float*)(ws + 71680000 + 57344 + 32768);   // 512

    // qbf aliases `sampled`: qbf is dead before sample_kernel writes sampled.
    unsigned short* qbf = sampled;

    prep_wcat<<<112, 256, 0, stream>>>(Wv, Woff, Wattn, WcatT);
    prep_w12<<<64, 256, 0, stream>>>(Wout1, Wout2, bout1, bout2, W12T, b12);
    qsum_kernel<<<2048, 256, 0, stream>>>(query, qpos, qbf);
    g1_kernel<<<1024, 256, 0, stream>>>(qbf, WcatT, bv, boff, battn,
                                        value_h, off_h, logits_h);
    sample_kernel<<<MTOT / 8, 256, 0, stream>>>(value_h, off_h, logits_h, sampled);
    g2_kernel<<<1024, 256, 0, stream>>>(sampled, W12T, b12, query, out);
}

// Round 13
// 104.470 us; speedup vs baseline: 1.2785x; 1.0508x over previous
//
#include <hip/hip_runtime.h>
#include <hip/hip_bf16.h>
#include <hip/hip_fp16.h>

// Problem constants (match setup_inputs): B=2, Y=X=200, N=40000, C=128, H=4, P=8, D=32
#define BQ 2
#define YY 200
#define XX 200
#define NQ 40000
#define CC 128
#define MTOT 80000   // BQ*NQ
#define NCOL 224     // 128 (value) + 64 (off) + 32 (attn logits)
#define NTILES 5000  // MTOT/16

typedef __attribute__((ext_vector_type(8))) short short8;
typedef __attribute__((ext_vector_type(4))) short short4v;
typedef __attribute__((ext_vector_type(4))) float f32x4;

static __device__ __forceinline__ unsigned short f2bf(float f) {
    union { float f; unsigned int u; } v; v.f = f;
    unsigned int r = v.u + 0x7FFF + ((v.u >> 16) & 1);  // round-to-nearest-even
    return (unsigned short)(r >> 16);
}
static __device__ __forceinline__ unsigned short f2bf_hw(float f) {
    __hip_bfloat16 h = __float2bfloat16(f);
    unsigned short s;
    __builtin_memcpy(&s, &h, 2);
    return s;
}
static __device__ __forceinline__ __half2 u2h2(unsigned int u) {
    __half2 h; __builtin_memcpy(&h, &u, 4); return h;
}
static __device__ __forceinline__ unsigned int h22u(__half2 h) {
    unsigned int u; __builtin_memcpy(&u, &h, 4); return u;
}
static __device__ __forceinline__ short h2s(__half h) {
    short s; __builtin_memcpy(&s, &h, 2); return s;
}
static __device__ __forceinline__ unsigned int packh2(float a, float b) {
    return h22u(__floats2half2_rn(a, b));   // low = a, high = b
}

// ---- prep (merged): WcatT[224][128] bf16 ; W12T[128][128] bf16 ; b12 ----
__global__ void prep_kernel(const float* __restrict__ Wv, const float* __restrict__ Woff,
                            const float* __restrict__ Wattn,
                            const float* __restrict__ Wout1, const float* __restrict__ Wout2,
                            const float* __restrict__ bout1, const float* __restrict__ bout2,
                            unsigned short* __restrict__ WcatT,
                            unsigned short* __restrict__ W12T, float* __restrict__ b12) {
    if (blockIdx.x < 112) {
        int idx = blockIdx.x * 256 + threadIdx.x;       // 224*128 = 28672
        if (idx >= NCOL * CC) return;
        int c = idx >> 7, k = idx & 127;
        float w = (c < 128) ? Wv[k * 128 + c]
                : (c < 192) ? Woff[k * 64 + (c - 128)]
                            : Wattn[k * 32 + (c - 192)];
        WcatT[c * 128 + k] = f2bf(w);
    } else {
        int idx = (blockIdx.x - 112) * 256 + threadIdx.x;   // 16384
        int c = idx >> 7, k = idx & 127;
        float s = 0.f;
        for (int j = 0; j < 128; ++j) s += Wout1[k * 128 + j] * Wout2[j * 128 + c];
        W12T[c * 128 + k] = f2bf(s);
        if (k == 0) {
            float t = bout2[c];
            for (int j = 0; j < 128; ++j) t += bout1[j] * Wout2[j * 128 + c];
            b12[c] = t;
        }
    }
}

// ---- qsum: q_bf = bf16(query + qpos), pure streaming ----
__global__ __launch_bounds__(256) void qsum_kernel(const float* __restrict__ query,
                                                   const float* __restrict__ qpos,
                                                   unsigned short* __restrict__ qbf) {
    const size_t total = (size_t)MTOT * CC / 8;   // 1,280,000 chunks of 8 floats
    for (size_t c = (size_t)blockIdx.x * 256 + threadIdx.x; c < total;
         c += (size_t)gridDim.x * 256) {
        const float4* a = (const float4*)(query + c * 8);
        const float4* b = (const float4*)(qpos + c * 8);
        float4 a0 = a[0], a1 = a[1], b0 = b[0], b1 = b[1];
        short8 w;
        w[0] = (short)f2bf_hw(a0.x + b0.x); w[1] = (short)f2bf_hw(a0.y + b0.y);
        w[2] = (short)f2bf_hw(a0.z + b0.z); w[3] = (short)f2bf_hw(a0.w + b0.w);
        w[4] = (short)f2bf_hw(a1.x + b1.x); w[5] = (short)f2bf_hw(a1.y + b1.y);
        w[6] = (short)f2bf_hw(a1.z + b1.z); w[7] = (short)f2bf_hw(a1.w + b1.w);
        *(short8*)(qbf + c * 8) = w;
    }
}

// ---- G1: projection GEMM, B fully in REGISTERS (no LDS, no barrier).
// A = qbf (bf16, 64B/lane). 4 groups by blockIdx>>8 (siblings same XCD).
// Swapped-operand MFMA -> 4 consecutive output cols per lane.
// Outputs: value fp16, off fp16, logits fp16.
__global__ __launch_bounds__(256, 2) void g1_kernel(
    const unsigned short* __restrict__ qbf, const unsigned short* __restrict__ WcatT,
    const float* __restrict__ bv, const float* __restrict__ boff, const float* __restrict__ battn,
    unsigned short* __restrict__ value_h, unsigned short* __restrict__ off_h,
    unsigned short* __restrict__ logits_h)
{
    const int tid = threadIdx.x;
    const int group = blockIdx.x >> 8;         // 0..3, siblings same XCD
    const int gblk = blockIdx.x & 255;
    const int lane = tid & 63;
    const int arow = lane & 15, kq = lane >> 4;
    const int wid = gblk * 4 + (tid >> 6);     // 0..1023 within group
    const int tg0 = group * 4;
    const int NT = (group == 3) ? 2 : 4;

    short8 bf[4][4];
#pragma unroll
    for (int t = 0; t < 4; ++t) {
        if (t < NT) {
#pragma unroll
            for (int ks = 0; ks < 4; ++ks)
                bf[t][ks] = *(const short8*)(WcatT + (size_t)((tg0 + t) * 16 + arow) * 128 + ks * 32 + kq * 8);
        }
    }

    f32x4 biasv[4];
#pragma unroll
    for (int t = 0; t < 4; ++t) {
        if (t < NT) {
            const float* bp = (group < 2) ? (bv + (tg0 + t) * 16 + kq * 4)
                            : (group == 2) ? (boff + (tg0 + t - 8) * 16 + kq * 4)
                                           : (battn + (tg0 + t - 12) * 16 + kq * 4);
            float4 b4 = *(const float4*)bp;
            biasv[t] = (f32x4){b4.x, b4.y, b4.z, b4.w};
        }
    }

    for (int tile = wid; tile < NTILES; tile += 1024) {
        const char* pa = (const char*)qbf + (size_t)(tile * 16 + arow) * 256 + kq * 16;
        short8 af[4];
#pragma unroll
        for (int ks = 0; ks < 4; ++ks) af[ks] = *(const short8*)(pa + ks * 64);

        f32x4 acc[4];
#pragma unroll
        for (int t = 0; t < 4; ++t) acc[t] = biasv[t];

#pragma unroll
        for (int ks = 0; ks < 4; ++ks) {
#pragma unroll
            for (int t = 0; t < 4; ++t) {
                if (t < NT)   // swapped operands -> transposed fragment
                    acc[t] = __builtin_amdgcn_mfma_f32_16x16x32_bf16(bf[t][ks], af[ks], acc[t], 0, 0, 0);
            }
        }

        const int row = tile * 16 + arow;
        if (group < 2) {
#pragma unroll
            for (int t = 0; t < 4; ++t) {
                short4v pv;
                pv[0] = h2s(__float2half(acc[t][0])); pv[1] = h2s(__float2half(acc[t][1]));
                pv[2] = h2s(__float2half(acc[t][2])); pv[3] = h2s(__float2half(acc[t][3]));
                *(short4v*)(value_h + (size_t)row * 128 + (tg0 + t) * 16 + kq * 4) = pv;
            }
        } else if (group == 2) {
#pragma unroll
            for (int t = 0; t < 4; ++t) {
                uint2 pk;
                pk.x = packh2(acc[t][0], acc[t][1]);
                pk.y = packh2(acc[t][2], acc[t][3]);
                *(uint2*)(off_h + (size_t)row * 64 + (tg0 + t - 8) * 16 + kq * 4) = pk;
            }
        } else {
#pragma unroll
            for (int t = 0; t < 2; ++t) {
                uint2 pk;
                pk.x = packh2(acc[t][0], acc[t][1]);
                pk.y = packh2(acc[t][2], acc[t][3]);
                *(uint2*)(logits_h + (size_t)row * 32 + (tg0 + t - 12) * 16 + kq * 4) = pk;
            }
        }
    }
}

// ---- SG2 (fused sample + G2): 512 threads, 16 queries/block, 5000 blocks.
// Phases 1-2 = verified sample kernel (results to LDS tile instead of global);
// Phase 3 = verified g2 MFMA epilogue with A-fragments from LDS.
// Stile row pad +16B (272B stride): phase-3 ds_read_b128 spreads 64 lanes
// uniformly across all 8 bank-quads (bank = 4*(arow+kq) + 16*ks).
__global__ __launch_bounds__(512, 2) void sg2_kernel(
    const unsigned short* __restrict__ value_h, const unsigned short* __restrict__ off_h,
    const unsigned short* __restrict__ logits_h, const unsigned short* __restrict__ W12T,
    const float* __restrict__ b12, const float* __restrict__ query, float* __restrict__ out)
{
    __shared__ int4 SA[16][36];               // corner byte-addresses
    __shared__ int4 SW[16][36];               // dup'd half2 corner weights
    __shared__ unsigned char Stile[16 * 272]; // sampled tile, bf16 [16][128], row stride 272B

    const int tid = threadIdx.x;
    const int qi = tid >> 5;
    const int lane = tid & 31;
    const int r = blockIdx.x * 16 + qi;        // query row, 0..79999
    const int b = (r >= NQ) ? 1 : 0;
    const int n = r - b * NQ;
    const int yq = n / XX, xq = n - yq * XX;

    // ---- phase 1: per-sample setup (lane = h*8+p) ----
    {
        float lg = __half2float(*(const __half*)(logits_h + (size_t)r * 32 + lane));
        float m = lg;
        m = fmaxf(m, __shfl_xor(m, 1));
        m = fmaxf(m, __shfl_xor(m, 2));
        m = fmaxf(m, __shfl_xor(m, 4));
        float e = __expf(lg - m);
        float s = e;
        s += __shfl_xor(s, 1);
        s += __shfl_xor(s, 2);
        s += __shfl_xor(s, 4);
        float aw = e / s;

        // faithful reference quirk: x-coord = yq + off0, y-coord = xq + off1
        __half2 oh = u2h2(*(const unsigned int*)(off_h + (size_t)r * 64 + lane * 2));
        float gx = (float)yq + __low2float(oh);
        float gy = (float)xq + __high2float(oh);
        float fx = floorf(gx), fy = floorf(gy);
        int x0 = (int)fx, y0 = (int)fy;
        float wx1 = gx - fx, wy1 = gy - fy;
        float vx0 = ((unsigned)x0 < XX) ? 1.f : 0.f;
        float vx1 = ((unsigned)(x0 + 1) < XX) ? 1.f : 0.f;
        float vy0 = ((unsigned)y0 < YY) ? 1.f : 0.f;
        float vy1 = ((unsigned)(y0 + 1) < YY) ? 1.f : 0.f;
        int x0c = min(max(x0, 0), XX - 1);
        int x1c = min(max(x0 + 1, 0), XX - 1);
        int y0c = min(max(y0, 0), YY - 1);
        int y1c = min(max(y0 + 1, 0), YY - 1);
        int hb = (lane >> 3) * 64;                 // head byte offset within 256B row
        int rowA = y0c * XX, rowB = y1c * XX;
        int4 addrs;
        addrs.x = (rowA + x0c) * 256 + hb;
        addrs.y = (rowA + x1c) * 256 + hb;
        addrs.z = (rowB + x0c) * 256 + hb;
        addrs.w = (rowB + x1c) * 256 + hb;

        float wxa = (1.f - wx1) * vx0;
        float wxb = wx1 * vx1;
        float wya = aw * (1.f - wy1) * vy0;
        float wyb = aw * wy1 * vy1;
        int4 wts;
        wts.x = (int)h22u(__float2half2_rn(wxa * wya));   // w00
        wts.y = (int)h22u(__float2half2_rn(wxb * wya));   // w01
        wts.z = (int)h22u(__float2half2_rn(wxa * wyb));   // w10
        wts.w = (int)h22u(__float2half2_rn(wxb * wyb));   // w11

        const int slot = (lane & 7) * 4 + (lane >> 3);    // 4p + h
        SA[qi][slot] = addrs;
        SW[qi][slot] = wts;
    }
    __syncthreads();

    // ---- phase 2: lane = h*8 + yc*4 + quad; result -> Stile (LDS) ----
    {
        const char* vb = (const char*)(value_h + (size_t)b * NQ * 128);
        const int h = lane >> 3, yc = (lane >> 2) & 1, quad = lane & 3;
        const int cb = quad * 16;               // 16B (8 fp16 channels) within head row

        int2 a[8];
#pragma unroll
        for (int p = 0; p < 8; ++p)
            a[p] = *(const int2*)((const char*)&SA[qi][p * 4 + h] + yc * 8);

        uint4 d0[8], d1[8];
#pragma unroll
        for (int p = 0; p < 8; ++p) {
            d0[p] = *(const uint4*)(vb + a[p].x + cb);
            d1[p] = *(const uint4*)(vb + a[p].y + cb);
        }

        int2 w[8];
#pragma unroll
        for (int p = 0; p < 8; ++p)
            w[p] = *(const int2*)((const char*)&SW[qi][p * 4 + h] + yc * 8);

        __half2 acc0 = __float2half2_rn(0.f), acc1 = __float2half2_rn(0.f);
        __half2 acc2 = __float2half2_rn(0.f), acc3 = __float2half2_rn(0.f);

#pragma unroll
        for (int p = 0; p < 8; ++p) {
            __half2 wa = u2h2((unsigned int)w[p].x);
            __half2 wb = u2h2((unsigned int)w[p].y);
            acc0 = __hfma2(wa, u2h2(d0[p].x), acc0);
            acc1 = __hfma2(wa, u2h2(d0[p].y), acc1);
            acc2 = __hfma2(wa, u2h2(d0[p].z), acc2);
            acc3 = __hfma2(wa, u2h2(d0[p].w), acc3);
            acc0 = __hfma2(wb, u2h2(d1[p].x), acc0);
            acc1 = __hfma2(wb, u2h2(d1[p].y), acc1);
            acc2 = __hfma2(wb, u2h2(d1[p].z), acc2);
            acc3 = __hfma2(wb, u2h2(d1[p].w), acc3);
        }

        // combine the two y-rows (lanes yc=0/1 differ by bit 2)
        acc0 = __hadd2(acc0, u2h2((unsigned int)__shfl_xor((int)h22u(acc0), 4)));
        acc1 = __hadd2(acc1, u2h2((unsigned int)__shfl_xor((int)h22u(acc1), 4)));
        acc2 = __hadd2(acc2, u2h2((unsigned int)__shfl_xor((int)h22u(acc2), 4)));
        acc3 = __hadd2(acc3, u2h2((unsigned int)__shfl_xor((int)h22u(acc3), 4)));

        __half2 pa = (yc == 0) ? acc0 : acc2;
        __half2 pb = (yc == 0) ? acc1 : acc3;
        uint2 packed;
        packed.x = ((unsigned int)f2bf(__high2float(pa)) << 16) | (unsigned int)f2bf(__low2float(pa));
        packed.y = ((unsigned int)f2bf(__high2float(pb)) << 16) | (unsigned int)f2bf(__low2float(pb));
        *(uint2*)(Stile + qi * 272 + h * 64 + cb + yc * 8) = packed;
    }
    __syncthreads();

    // ---- phase 3: G2 MFMA. 8 waves, wave w -> col-tile w. A from Stile. ----
    {
        const int w = tid >> 6;
        const int lane64 = tid & 63;
        const int arow = lane64 & 15, kq = lane64 >> 4;
        const int qbase = blockIdx.x * 16;

        short8 bfr[4];
#pragma unroll
        for (int ks = 0; ks < 4; ++ks)
            bfr[ks] = *(const short8*)(W12T + (size_t)(w * 16 + arow) * 128 + ks * 32 + kq * 8);

        float4 b4 = *(const float4*)(b12 + w * 16 + kq * 4);
        f32x4 acc = (f32x4){b4.x, b4.y, b4.z, b4.w};

        short8 af[4];
#pragma unroll
        for (int ks = 0; ks < 4; ++ks)
            af[ks] = *(const short8*)(Stile + arow * 272 + ks * 64 + kq * 16);

#pragma unroll
        for (int ks = 0; ks < 4; ++ks)
            acc = __builtin_amdgcn_mfma_f32_16x16x32_bf16(bfr[ks], af[ks], acc, 0, 0, 0);

        size_t idx = (size_t)(qbase + arow) * 128 + w * 16 + kq * 4;
        float4 q4 = *(const float4*)(query + idx);
        float4 o = make_float4(acc[0] + q4.x, acc[1] + q4.y, acc[2] + q4.z, acc[3] + q4.w);
        *(float4*)(out + idx) = o;
    }
}

extern "C" void kernel_launch(void* const* d_in, const int* in_sizes, int n_in,
                              void* d_out, int out_size, void* d_ws, size_t ws_size,
                              hipStream_t stream) {
    const float* query = (const float*)d_in[0];
    const float* qpos  = (const float*)d_in[1];
    const float* Wv    = (const float*)d_in[2];
    const float* bv    = (const float*)d_in[3];
    const float* Woff  = (const float*)d_in[4];
    const float* boff  = (const float*)d_in[5];
    const float* Wattn = (const float*)d_in[6];
    const float* battn = (const float*)d_in[7];
    const float* Wout1 = (const float*)d_in[8];
    const float* bout1 = (const float*)d_in[9];
    const float* Wout2 = (const float*)d_in[10];
    const float* bout2 = (const float*)d_in[11];
    float* out = (float*)d_out;

    char* ws = (char*)d_ws;
    unsigned short* value_h  = (unsigned short*)(ws);                 // 80000*128*2 = 20,480,000 (fp16)
    unsigned short* off_h    = (unsigned short*)(ws + 20480000);      // 80000*64*2  = 10,240,000 (fp16)
    unsigned short* logits_h = (unsigned short*)(ws + 40960000);      // 80000*32*2  =  5,120,000 (fp16)
    unsigned short* qbf      = (unsigned short*)(ws + 51200000);      // 80000*128*2 = 20,480,000 (bf16)
    unsigned short* WcatT    = (unsigned short*)(ws + 71680000);      // 224*128*2   = 57,344
    unsigned short* W12T     = (unsigned short*)(ws + 71680000 + 57344);  // 128*128*2 = 32,768
    float*          b12      = (float*)(ws + 71680000 + 57344 + 32768);   // 512

    prep_kernel<<<176, 256, 0, stream>>>(Wv, Woff, Wattn, Wout1, Wout2, bout1, bout2,
                                         WcatT, W12T, b12);
    qsum_kernel<<<2048, 256, 0, stream>>>(query, qpos, qbf);
    g1_kernel<<<1024, 256, 0, stream>>>(qbf, WcatT, bv, boff, battn,
                                        value_h, off_h, logits_h);
    sg2_kernel<<<NTILES, 512, 0, stream>>>(value_h, off_h, logits_h, W12T, b12, query, out);
}

// Round 14
// 102.187 us; speedup vs baseline: 1.3071x; 1.0223x over previous
//
#include <hip/hip_runtime.h>
#include <hip/hip_bf16.h>
#include <hip/hip_fp16.h>

// Problem constants (match setup_inputs): B=2, Y=X=200, N=40000, C=128, H=4, P=8, D=32
#define BQ 2
#define YY 200
#define XX 200
#define NQ 40000
#define CC 128
#define MTOT 80000   // BQ*NQ
#define NCOL 224     // 128 (value) + 64 (off) + 32 (attn logits)
#define NTILES 5000  // MTOT/16

typedef __attribute__((ext_vector_type(8))) short short8;
typedef __attribute__((ext_vector_type(4))) short short4v;
typedef __attribute__((ext_vector_type(4))) float f32x4;

static __device__ __forceinline__ unsigned short f2bf(float f) {
    union { float f; unsigned int u; } v; v.f = f;
    unsigned int r = v.u + 0x7FFF + ((v.u >> 16) & 1);  // round-to-nearest-even
    return (unsigned short)(r >> 16);
}
static __device__ __forceinline__ unsigned short f2bf_hw(float f) {
    __hip_bfloat16 h = __float2bfloat16(f);
    unsigned short s;
    __builtin_memcpy(&s, &h, 2);
    return s;
}
static __device__ __forceinline__ __half2 u2h2(unsigned int u) {
    __half2 h; __builtin_memcpy(&h, &u, 4); return h;
}
static __device__ __forceinline__ unsigned int h22u(__half2 h) {
    unsigned int u; __builtin_memcpy(&u, &h, 4); return u;
}
static __device__ __forceinline__ short h2s(__half h) {
    short s; __builtin_memcpy(&s, &h, 2); return s;
}
static __device__ __forceinline__ unsigned int packh2(float a, float b) {
    return h22u(__floats2half2_rn(a, b));   // low = a, high = b
}

// ---- prep (merged): WcatT[224][128] bf16 ; W12T[128][128] bf16 ; b12 ----
__global__ void prep_kernel(const float* __restrict__ Wv, const float* __restrict__ Woff,
                            const float* __restrict__ Wattn,
                            const float* __restrict__ Wout1, const float* __restrict__ Wout2,
                            const float* __restrict__ bout1, const float* __restrict__ bout2,
                            unsigned short* __restrict__ WcatT,
                            unsigned short* __restrict__ W12T, float* __restrict__ b12) {
    if (blockIdx.x < 112) {
        int idx = blockIdx.x * 256 + threadIdx.x;       // 224*128 = 28672
        if (idx >= NCOL * CC) return;
        int c = idx >> 7, k = idx & 127;
        float w = (c < 128) ? Wv[k * 128 + c]
                : (c < 192) ? Woff[k * 64 + (c - 128)]
                            : Wattn[k * 32 + (c - 192)];
        WcatT[c * 128 + k] = f2bf(w);
    } else {
        int idx = (blockIdx.x - 112) * 256 + threadIdx.x;   // 16384
        int c = idx >> 7, k = idx & 127;
        float s = 0.f;
        for (int j = 0; j < 128; ++j) s += Wout1[k * 128 + j] * Wout2[j * 128 + c];
        W12T[c * 128 + k] = f2bf(s);
        if (k == 0) {
            float t = bout2[c];
            for (int j = 0; j < 128; ++j) t += bout1[j] * Wout2[j * 128 + c];
            b12[c] = t;
        }
    }
}

// ---- qsum: q_bf = bf16(query + qpos), pure streaming ----
__global__ __launch_bounds__(256) void qsum_kernel(const float* __restrict__ query,
                                                   const float* __restrict__ qpos,
                                                   unsigned short* __restrict__ qbf) {
    const size_t total = (size_t)MTOT * CC / 8;   // 1,280,000 chunks of 8 floats
    for (size_t c = (size_t)blockIdx.x * 256 + threadIdx.x; c < total;
         c += (size_t)gridDim.x * 256) {
        const float4* a = (const float4*)(query + c * 8);
        const float4* b = (const float4*)(qpos + c * 8);
        float4 a0 = a[0], a1 = a[1], b0 = b[0], b1 = b[1];
        short8 w;
        w[0] = (short)f2bf_hw(a0.x + b0.x); w[1] = (short)f2bf_hw(a0.y + b0.y);
        w[2] = (short)f2bf_hw(a0.z + b0.z); w[3] = (short)f2bf_hw(a0.w + b0.w);
        w[4] = (short)f2bf_hw(a1.x + b1.x); w[5] = (short)f2bf_hw(a1.y + b1.y);
        w[6] = (short)f2bf_hw(a1.z + b1.z); w[7] = (short)f2bf_hw(a1.w + b1.w);
        *(short8*)(qbf + c * 8) = w;
    }
}

// ---- G1: projection GEMM, B fully in REGISTERS (no LDS, no barrier).
// A = qbf (bf16, 64B/lane). 4 groups by blockIdx>>8 (siblings same XCD).
// Swapped-operand MFMA -> 4 consecutive output cols per lane.
// Outputs: value fp16, off fp16, logits fp16.
__global__ __launch_bounds__(256, 2) void g1_kernel(
    const unsigned short* __restrict__ qbf, const unsigned short* __restrict__ WcatT,
    const float* __restrict__ bv, const float* __restrict__ boff, const float* __restrict__ battn,
    unsigned short* __restrict__ value_h, unsigned short* __restrict__ off_h,
    unsigned short* __restrict__ logits_h)
{
    const int tid = threadIdx.x;
    const int group = blockIdx.x >> 8;         // 0..3, siblings same XCD
    const int gblk = blockIdx.x & 255;
    const int lane = tid & 63;
    const int arow = lane & 15, kq = lane >> 4;
    const int wid = gblk * 4 + (tid >> 6);     // 0..1023 within group
    const int tg0 = group * 4;
    const int NT = (group == 3) ? 2 : 4;

    short8 bf[4][4];
#pragma unroll
    for (int t = 0; t < 4; ++t) {
        if (t < NT) {
#pragma unroll
            for (int ks = 0; ks < 4; ++ks)
                bf[t][ks] = *(const short8*)(WcatT + (size_t)((tg0 + t) * 16 + arow) * 128 + ks * 32 + kq * 8);
        }
    }

    f32x4 biasv[4];
#pragma unroll
    for (int t = 0; t < 4; ++t) {
        if (t < NT) {
            const float* bp = (group < 2) ? (bv + (tg0 + t) * 16 + kq * 4)
                            : (group == 2) ? (boff + (tg0 + t - 8) * 16 + kq * 4)
                                           : (battn + (tg0 + t - 12) * 16 + kq * 4);
            float4 b4 = *(const float4*)bp;
            biasv[t] = (f32x4){b4.x, b4.y, b4.z, b4.w};
        }
    }

    for (int tile = wid; tile < NTILES; tile += 1024) {
        const char* pa = (const char*)qbf + (size_t)(tile * 16 + arow) * 256 + kq * 16;
        short8 af[4];
#pragma unroll
        for (int ks = 0; ks < 4; ++ks) af[ks] = *(const short8*)(pa + ks * 64);

        f32x4 acc[4];
#pragma unroll
        for (int t = 0; t < 4; ++t) acc[t] = biasv[t];

#pragma unroll
        for (int ks = 0; ks < 4; ++ks) {
#pragma unroll
            for (int t = 0; t < 4; ++t) {
                if (t < NT)   // swapped operands -> transposed fragment
                    acc[t] = __builtin_amdgcn_mfma_f32_16x16x32_bf16(bf[t][ks], af[ks], acc[t], 0, 0, 0);
            }
        }

        const int row = tile * 16 + arow;
        if (group < 2) {
#pragma unroll
            for (int t = 0; t < 4; ++t) {
                short4v pv;
                pv[0] = h2s(__float2half(acc[t][0])); pv[1] = h2s(__float2half(acc[t][1]));
                pv[2] = h2s(__float2half(acc[t][2])); pv[3] = h2s(__float2half(acc[t][3]));
                *(short4v*)(value_h + (size_t)row * 128 + (tg0 + t) * 16 + kq * 4) = pv;
            }
        } else if (group == 2) {
#pragma unroll
            for (int t = 0; t < 4; ++t) {
                uint2 pk;
                pk.x = packh2(acc[t][0], acc[t][1]);
                pk.y = packh2(acc[t][2], acc[t][3]);
                *(uint2*)(off_h + (size_t)row * 64 + (tg0 + t - 8) * 16 + kq * 4) = pk;
            }
        } else {
#pragma unroll
            for (int t = 0; t < 2; ++t) {
                uint2 pk;
                pk.x = packh2(acc[t][0], acc[t][1]);
                pk.y = packh2(acc[t][2], acc[t][3]);
                *(uint2*)(logits_h + (size_t)row * 32 + (tg0 + t - 12) * 16 + kq * 4) = pk;
            }
        }
    }
}

// ---- SG2 (fused sample + G2): 512 threads, 16 queries/block, 5000 blocks.
// Phase 2 uses sched_barrier(0) fences to FORCE all 16 gathers to issue before
// any consumer (compiler otherwise re-serializes into ~4-load chunks; round-13
// evidence: VGPR=32, 1.43 TB/s = Little's-law limit at 4 loads in flight).
__global__ __launch_bounds__(512, 2) void sg2_kernel(
    const unsigned short* __restrict__ value_h, const unsigned short* __restrict__ off_h,
    const unsigned short* __restrict__ logits_h, const unsigned short* __restrict__ W12T,
    const float* __restrict__ b12, const float* __restrict__ query, float* __restrict__ out)
{
    __shared__ int4 SA[16][36];               // corner byte-addresses
    __shared__ int4 SW[16][36];               // dup'd half2 corner weights
    __shared__ unsigned char Stile[16 * 272]; // sampled tile, bf16 [16][128], row stride 272B

    const int tid = threadIdx.x;
    const int qi = tid >> 5;
    const int lane = tid & 31;
    const int r = blockIdx.x * 16 + qi;        // query row, 0..79999
    const int b = (r >= NQ) ? 1 : 0;
    const int n = r - b * NQ;
    const int yq = n / XX, xq = n - yq * XX;

    // ---- phase 1: per-sample setup (lane = h*8+p) ----
    {
        float lg = __half2float(*(const __half*)(logits_h + (size_t)r * 32 + lane));
        float m = lg;
        m = fmaxf(m, __shfl_xor(m, 1));
        m = fmaxf(m, __shfl_xor(m, 2));
        m = fmaxf(m, __shfl_xor(m, 4));
        float e = __expf(lg - m);
        float s = e;
        s += __shfl_xor(s, 1);
        s += __shfl_xor(s, 2);
        s += __shfl_xor(s, 4);
        float aw = e / s;

        // faithful reference quirk: x-coord = yq + off0, y-coord = xq + off1
        __half2 oh = u2h2(*(const unsigned int*)(off_h + (size_t)r * 64 + lane * 2));
        float gx = (float)yq + __low2float(oh);
        float gy = (float)xq + __high2float(oh);
        float fx = floorf(gx), fy = floorf(gy);
        int x0 = (int)fx, y0 = (int)fy;
        float wx1 = gx - fx, wy1 = gy - fy;
        float vx0 = ((unsigned)x0 < XX) ? 1.f : 0.f;
        float vx1 = ((unsigned)(x0 + 1) < XX) ? 1.f : 0.f;
        float vy0 = ((unsigned)y0 < YY) ? 1.f : 0.f;
        float vy1 = ((unsigned)(y0 + 1) < YY) ? 1.f : 0.f;
        int x0c = min(max(x0, 0), XX - 1);
        int x1c = min(max(x0 + 1, 0), XX - 1);
        int y0c = min(max(y0, 0), YY - 1);
        int y1c = min(max(y0 + 1, 0), YY - 1);
        int hb = (lane >> 3) * 64;                 // head byte offset within 256B row
        int rowA = y0c * XX, rowB = y1c * XX;
        int4 addrs;
        addrs.x = (rowA + x0c) * 256 + hb;
        addrs.y = (rowA + x1c) * 256 + hb;
        addrs.z = (rowB + x0c) * 256 + hb;
        addrs.w = (rowB + x1c) * 256 + hb;

        float wxa = (1.f - wx1) * vx0;
        float wxb = wx1 * vx1;
        float wya = aw * (1.f - wy1) * vy0;
        float wyb = aw * wy1 * vy1;
        int4 wts;
        wts.x = (int)h22u(__float2half2_rn(wxa * wya));   // w00
        wts.y = (int)h22u(__float2half2_rn(wxb * wya));   // w01
        wts.z = (int)h22u(__float2half2_rn(wxa * wyb));   // w10
        wts.w = (int)h22u(__float2half2_rn(wxb * wyb));   // w11

        const int slot = (lane & 7) * 4 + (lane >> 3);    // 4p + h
        SA[qi][slot] = addrs;
        SW[qi][slot] = wts;
    }
    __syncthreads();

    // ---- phase 2: lane = h*8 + yc*4 + quad; result -> Stile (LDS) ----
    {
        const char* vb = (const char*)(value_h + (size_t)b * NQ * 128);
        const int h = lane >> 3, yc = (lane >> 2) & 1, quad = lane & 3;
        const int cb = quad * 16;               // 16B (8 fp16 channels) within head row

        int2 a[8];
#pragma unroll
        for (int p = 0; p < 8; ++p)
            a[p] = *(const int2*)((const char*)&SA[qi][p * 4 + h] + yc * 8);

        // issue ALL 16 gathers; fence pins them before any consumer
        uint4 d0[8], d1[8];
#pragma unroll
        for (int p = 0; p < 8; ++p) {
            d0[p] = *(const uint4*)(vb + a[p].x + cb);
            d1[p] = *(const uint4*)(vb + a[p].y + cb);
        }
        __builtin_amdgcn_sched_barrier(0);   // no instruction may cross: 16 loads stay batched

        int2 w[8];
#pragma unroll
        for (int p = 0; p < 8; ++p)
            w[p] = *(const int2*)((const char*)&SW[qi][p * 4 + h] + yc * 8);

        __half2 acc0 = __float2half2_rn(0.f), acc1 = __float2half2_rn(0.f);
        __half2 acc2 = __float2half2_rn(0.f), acc3 = __float2half2_rn(0.f);

#pragma unroll
        for (int p = 0; p < 8; ++p) {
            __half2 wa = u2h2((unsigned int)w[p].x);
            __half2 wb = u2h2((unsigned int)w[p].y);
            acc0 = __hfma2(wa, u2h2(d0[p].x), acc0);
            acc1 = __hfma2(wa, u2h2(d0[p].y), acc1);
            acc2 = __hfma2(wa, u2h2(d0[p].z), acc2);
            acc3 = __hfma2(wa, u2h2(d0[p].w), acc3);
            acc0 = __hfma2(wb, u2h2(d1[p].x), acc0);
            acc1 = __hfma2(wb, u2h2(d1[p].y), acc1);
            acc2 = __hfma2(wb, u2h2(d1[p].z), acc2);
            acc3 = __hfma2(wb, u2h2(d1[p].w), acc3);
        }

        // combine the two y-rows (lanes yc=0/1 differ by bit 2)
        acc0 = __hadd2(acc0, u2h2((unsigned int)__shfl_xor((int)h22u(acc0), 4)));
        acc1 = __hadd2(acc1, u2h2((unsigned int)__shfl_xor((int)h22u(acc1), 4)));
        acc2 = __hadd2(acc2, u2h2((unsigned int)__shfl_xor((int)h22u(acc2), 4)));
        acc3 = __hadd2(acc3, u2h2((unsigned int)__shfl_xor((int)h22u(acc3), 4)));

        __half2 pa = (yc == 0) ? acc0 : acc2;
        __half2 pb = (yc == 0) ? acc1 : acc3;
        uint2 packed;
        packed.x = ((unsigned int)f2bf(__high2float(pa)) << 16) | (unsigned int)f2bf(__low2float(pa));
        packed.y = ((unsigned int)f2bf(__high2float(pb)) << 16) | (unsigned int)f2bf(__low2float(pb));
        *(uint2*)(Stile + qi * 272 + h * 64 + cb + yc * 8) = packed;
    }
    __syncthreads();

    // ---- phase 3: G2 MFMA. 8 waves, wave w -> col-tile w. A from Stile. ----
    {
        const int w = tid >> 6;
        const int lane64 = tid & 63;
        const int arow = lane64 & 15, kq = lane64 >> 4;
        const int qbase = blockIdx.x * 16;

        short8 bfr[4];
#pragma unroll
        for (int ks = 0; ks < 4; ++ks)
            bfr[ks] = *(const short8*)(W12T + (size_t)(w * 16 + arow) * 128 + ks * 32 + kq * 8);

        float4 b4 = *(const float4*)(b12 + w * 16 + kq * 4);
        f32x4 acc = (f32x4){b4.x, b4.y, b4.z, b4.w};

        short8 af[4];
#pragma unroll
        for (int ks = 0; ks < 4; ++ks)
            af[ks] = *(const short8*)(Stile + arow * 272 + ks * 64 + kq * 16);

#pragma unroll
        for (int ks = 0; ks < 4; ++ks)
            acc = __builtin_amdgcn_mfma_f32_16x16x32_bf16(bfr[ks], af[ks], acc, 0, 0, 0);

        size_t idx = (size_t)(qbase + arow) * 128 + w * 16 + kq * 4;
        float4 q4 = *(const float4*)(query + idx);
        float4 o = make_float4(acc[0] + q4.x, acc[1] + q4.y, acc[2] + q4.z, acc[3] + q4.w);
        *(float4*)(out + idx) = o;
    }
}

extern "C" void kernel_launch(void* const* d_in, const int* in_sizes, int n_in,
                              void* d_out, int out_size, void* d_ws, size_t ws_size,
                              hipStream_t stream) {
    const float* query = (const float*)d_in[0];
    const float* qpos  = (const float*)d_in[1];
    const float* Wv    = (const float*)d_in[2];
    const float* bv    = (const float*)d_in[3];
    const float* Woff  = (const float*)d_in[4];
    const float* boff  = (const float*)d_in[5];
    const float* Wattn = (const float*)d_in[6];
    const float* battn = (const float*)d_in[7];
    const float* Wout1 = (const float*)d_in[8];
    const float* bout1 = (const float*)d_in[9];
    const float* Wout2 = (const float*)d_in[10];
    const float* bout2 = (const float*)d_in[11];
    float* out = (float*)d_out;

    char* ws = (char*)d_ws;
    unsigned short* value_h  = (unsigned short*)(ws);                 // 80000*128*2 = 20,480,000 (fp16)
    unsigned short* off_h    = (unsigned short*)(ws + 20480000);      // 80000*64*2  = 10,240,000 (fp16)
    unsigned short* logits_h = (unsigned short*)(ws + 40960000);      // 80000*32*2  =  5,120,000 (fp16)
    unsigned short* qbf      = (unsigned short*)(ws + 51200000);      // 80000*128*2 = 20,480,000 (bf16)
    unsigned short* WcatT    = (unsigned short*)(ws + 71680000);      // 224*128*2   = 57,344
    unsigned short* W12T     = (unsigned short*)(ws + 71680000 + 57344);  // 128*128*2 = 32,768
    float*          b12      = (float*)(ws + 71680000 + 57344 + 32768);   // 512

    prep_kernel<<<176, 256, 0, stream>>>(Wv, Woff, Wattn, Wout1, Wout2, bout1, bout2,
                                         WcatT, W12T, b12);
    qsum_kernel<<<2048, 256, 0, stream>>>(query, qpos, qbf);
    g1_kernel<<<1024, 256, 0, stream>>>(qbf, WcatT, bv, boff, battn,
                                        value_h, off_h, logits_h);
    sg2_kernel<<<NTILES, 512, 0, stream>>>(value_h, off_h, logits_h, W12T, b12, query, out);
}